// Round 12
// baseline (47.484 us; speedup 1.0000x reference)
//
#include <hip/hip_runtime.h>

#define LOG2E 1.4426950408889634f
#define NEG50L (-50.0f * LOG2E)   // -0.5/sigma_color^2 * log2(e)
#define M100L (100.0f * LOG2E)    // = -2 * NEG50L

// compile-time problem shape (bench fixed at 16x512x512x3 f32 NHWC)
#define B_ 16
#define H_ 512
#define W_ 512

#define TILE_C 128           // columns per block (CW per lane)
#define CW 2                 // adjacent columns per lane
#define TH 2                 // output rows per thread
#define TILE_R 8             // output rows per block (4 waves x TH)
#define LR (TILE_R + 4)      // 12 LDS rows (halo'd)
#define LC (TILE_C + 4)      // 132 LDS cols (halo'd)
#define NTEX (LR * LC)       // 1584 texels

#define EXP2(x) __builtin_amdgcn_exp2f(x)

typedef float f4 __attribute__((ext_vector_type(4)));               // LDS texel
typedef float f4u __attribute__((ext_vector_type(4), aligned(4)));  // unaligned store
typedef float f3 __attribute__((ext_vector_type(3), aligned(4)));   // 12B global load
typedef float f2 __attribute__((ext_vector_type(2)));               // v_pk_*_f32
typedef float f2u __attribute__((ext_vector_type(2), aligned(4)));

// R10 skeleton (one-shot blocks — R11's persistent strip regressed) with
// CW=2 horizontal register blocking. R11's accounting showed the LDS pipe
// at ~22us of the 37.8us runtime: every texel was ds_read 5x horizontally
// (300B/px). Each lane now owns 2 adjacent columns: 6 texels/row serve
// both 5-windows -> 3 texels/px/row, LDS traffic halved (~11us), VALU
// unchanged -> VALU duty rises toward its ~26us floor.
// qsp table dropped for scalar qc + literal spatial (+1 add/tap) to keep
// VGPR ~75 (qsp for 4 centers = 24 regs, tier risk).
__global__ __launch_bounds__(256) void bilateral_kernel(
    const float* __restrict__ x, float* __restrict__ out)
{
    __shared__ f4 tile[NTEX];          // 25,344 B  {r,g,b,1}
    __shared__ float tileq[NTEX];      //  6,336 B  q = -50L*|rgb|^2 (0 if OOB)

    const int bid = blockIdx.x;
    const int ct = bid & 3;            // 4 col tiles
    const int rt = (bid >> 2) & 63;    // 64 row tiles
    const int b0 = bid >> 8;           // 16 batches
    const int c0 = ct * TILE_C;
    const int h0 = rt * TILE_R;

    const float* __restrict__ img = x + (size_t)b0 * (H_ * W_ * 3);
    float* __restrict__ oimg      = out + (size_t)b0 * (H_ * W_ * 3);

    // ---- stage 12x132 texels; clamped address (always valid), cndmask zeros.
#pragma unroll
    for (int k = 0; k < 7; ++k) {
        const int s = (int)threadIdx.x + k * 256;
        if (k < 6 || s < NTEX) {               // k<6 folds; last iter guarded
            const int lr = s / LC;             // magic-mul (constant divisor)
            const int lc_ = s - lr * LC;
            const int gr = h0 - 2 + lr;
            const int gc = c0 - 2 + lc_;
            const int cr_ = min(max(gr, 0), H_ - 1);
            const int cc_ = min(max(gc, 0), W_ - 1);
            const bool ok = (gr == cr_) && (gc == cc_);
            const f3 v = *(const f3*)(img + (cr_ * W_ + cc_) * 3);
            f4 t;
            t.x = ok ? v.x : 0.0f;
            t.y = ok ? v.y : 0.0f;
            t.z = ok ? v.z : 0.0f;
            t.w = 1.0f;                        // den rides .w via pk_fma
            float n2 = t.x * t.x;
            n2 = fmaf(t.y, t.y, n2);
            n2 = fmaf(t.z, t.z, n2);
            tile[s] = t;                       // ds_write_b128
            tileq[s] = NEG50L * n2;            // ds_write_b32
        }
    }
    __syncthreads();

    const int lane  = threadIdx.x & 63;
    const int wv    = threadIdx.x >> 6;        // wave -> 2-row group
    const int rbase = wv * TH;                 // first LDS row of my stream
    const int cb    = lane * CW;               // first LDS col of my window

    // per-center state: kc = 100L*c, qc; packed accumulators with center
    // tap (w==1) pre-folded.
    float kc[TH][CW][3], qc[TH][CW];
    f2 accRG[TH][CW], accB1[TH][CW];
#pragma unroll
    for (int j = 0; j < TH; ++j)
#pragma unroll
        for (int cc = 0; cc < CW; ++cc) {
            const int ci = (rbase + j + 2) * LC + (cb + 2 + cc);
            const f4 c = tile[ci];
            kc[j][cc][0] = M100L * c.x;
            kc[j][cc][1] = M100L * c.y;
            kc[j][cc][2] = M100L * c.z;
            qc[j][cc] = tileq[ci];
            accRG[j][cc] = (f2){c.x, c.y};
            accB1[j][cc] = (f2){c.z, 1.0f};
        }

    // ---- stream 6 LDS rows; 6 texels serve both columns' 5-windows ----
#pragma unroll
    for (int r = 0; r < TH + 4; ++r) {
        const int tb = (rbase + r) * LC + cb;  // even -> q pairs 8B-aligned
        f4 row[6];
        float rowq[6];
#pragma unroll
        for (int d = 0; d < 6; ++d)
            row[d] = tile[tb + d];             // ds_read_b128
#pragma unroll
        for (int d = 0; d < 3; ++d)
            *(f2*)&rowq[2 * d] = *(const f2*)&tileq[tb + 2 * d];  // ds_read_b64

#pragma unroll
        for (int j = 0; j < TH; ++j) {
            if (r - j >= 0 && r - j <= 4) {    // unroll-const
                const int dy = r - j;
                const int sdy = (dy - 2) * (dy - 2);
#pragma unroll
                for (int cc = 0; cc < CW; ++cc) {
#pragma unroll
                    for (int dx = 0; dx < 5; ++dx) {
                        if (dy == 2 && dx == 2) continue;   // pre-folded
                        const f4 n = row[cc + dx];
                        float s = fmaf(n.x, kc[j][cc][0], rowq[cc + dx]);
                        s = fmaf(n.y, kc[j][cc][1], s);
                        s = fmaf(n.z, kc[j][cc][2], s);
                        const float sp = -0.5f * LOG2E *
                            (float)(sdy + (dx - 2) * (dx - 2));
                        const float arg = (s + qc[j][cc]) + sp;  // sp: literal
                        const float w = EXP2(arg);
                        const f2 w2 = {w, w};
                        const f2 nRG = {n.x, n.y};
                        const f2 nB1 = {n.z, n.w};           // {b, 1.0}
                        accRG[j][cc] =
                            __builtin_elementwise_fma(w2, nRG, accRG[j][cc]);
                        accB1[j][cc] =
                            __builtin_elementwise_fma(w2, nB1, accB1[j][cc]);
                    }
                }
            }
        }
    }

    // ---- epilogue: 2 adjacent px per row-center = 24B contiguous ----
#pragma unroll
    for (int j = 0; j < TH; ++j) {
        const float inv0 = __builtin_amdgcn_rcpf(accB1[j][0].y);   // den >= 1
        const float inv1 = __builtin_amdgcn_rcpf(accB1[j][1].y);
        float* op = oimg +
            ((size_t)(h0 + rbase + j) * W_ + (c0 + cb)) * 3;
        f4u v0 = {accRG[j][0].x * inv0, accRG[j][0].y * inv0,
                  accB1[j][0].x * inv0, accRG[j][1].x * inv1};
        f2u v1 = {accRG[j][1].y * inv1, accB1[j][1].x * inv1};
        *(f4u*)op = v0;                        // global_store_dwordx4
        *(f2u*)(op + 4) = v1;                  // global_store_dwordx2
    }
}

extern "C" void kernel_launch(void* const* d_in, const int* in_sizes, int n_in,
                              void* d_out, int out_size, void* d_ws, size_t ws_size,
                              hipStream_t stream) {
    const float* x = (const float*)d_in[0];
    float* out = (float*)d_out;

    const int grid = B_ * (W_ / TILE_C) * (H_ / TILE_R);   // 16*4*64 = 4096
    const int block = 256;

    bilateral_kernel<<<grid, block, 0, stream>>>(x, out);
}

// Round 13
// 37.013 us; speedup vs baseline: 1.2829x; 1.2829x over previous
//
#include <hip/hip_runtime.h>

#define LOG2E 1.4426950408889634f
#define NEG50L (-50.0f * LOG2E)   // -0.5/sigma_color^2 * log2(e)
#define M100L (100.0f * LOG2E)    // = -2 * NEG50L

// compile-time problem shape (bench fixed at 16x512x512x3 f32 NHWC)
#define B_ 16
#define H_ 512
#define W_ 512

#define TILE_C 64            // columns per block (one lane each; 16B LDS lane
                             // stride -> PROVEN conflict-free, unlike R12)
#define TH 4                 // output rows per thread (vertical amortization:
                             // each streamed row serves 2.5 centers avg vs 1.67)
#define TILE_R 16            // output rows per block (4 waves x TH)
#define LR (TILE_R + 4)      // 20 LDS rows (halo'd)
#define LC (TILE_C + 4)      // 68 LDS cols (halo'd)
#define NTEX (LR * LC)       // 1360 texels

#define EXP2(x) __builtin_amdgcn_exp2f(x)

typedef float f4 __attribute__((ext_vector_type(4)));              // LDS texel
typedef float f3 __attribute__((ext_vector_type(3), aligned(4))); // 12B global load
typedef float f2 __attribute__((ext_vector_type(2)));             // v_pk_*_f32

// map spatial dist^2 (values 0,1,2,4,5,8) -> dense index 0..5
__device__ __forceinline__ constexpr int sidx(int sd) {
    return (sd == 0) ? 0 : (sd == 1) ? 1 : (sd == 2) ? 2
         : (sd == 4) ? 3 : (sd == 5) ? 4 : 5;
}

// R10 pipeline (37.8us) with TH 2->4: R11's pipe accounting put the LDS
// pipe at ~30us vs VALU ~26us; R12's CW=2 horizontal fix broke bank
// conflicts (32B lane stride). TH=4 cuts LDS traffic VERTICALLY instead:
// per-px main-loop LDS 160 -> 110 cyc at unchanged 16B dense stride.
// Register cost (~+30: kc/qsp/acc for 4 centers) is occupancy-free:
// LDS 27.2KB caps residency at 5 blocks = 20 waves/CU, which the 5-wave
// VGPR tier (<=102) matches anyway.
__global__ __launch_bounds__(256) void bilateral_kernel(
    const float* __restrict__ x, float* __restrict__ out)
{
    __shared__ f4 tile[NTEX];          // 21,760 B  {r,g,b,1}
    __shared__ float tileq[NTEX];      //  5,440 B  q = -50L*|rgb|^2 (0 if OOB)

    const int bid = blockIdx.x;
    const int ct = bid & 7;            // 8 col tiles
    const int rt = (bid >> 3) & 31;    // 32 row tiles
    const int b0 = bid >> 8;           // 16 batches
    const int c0 = ct * TILE_C;
    const int h0 = rt * TILE_R;

    const float* __restrict__ img = x + (size_t)b0 * (H_ * W_ * 3);
    float* __restrict__ oimg      = out + (size_t)b0 * (H_ * W_ * 3);

    // ---- stage 20x68 texels; clamped address (always valid), cndmask zeros.
#pragma unroll
    for (int k = 0; k < 6; ++k) {
        const int s = (int)threadIdx.x + k * 256;
        if (k < 5 || s < NTEX) {               // k<5 folds; last iter guarded
            const int lr = s / LC;             // magic-mul (constant divisor)
            const int lc_ = s - lr * LC;
            const int gr = h0 - 2 + lr;
            const int gc = c0 - 2 + lc_;
            const int cr_ = min(max(gr, 0), H_ - 1);
            const int cc_ = min(max(gc, 0), W_ - 1);
            const bool ok = (gr == cr_) && (gc == cc_);
            const f3 v = *(const f3*)(img + (cr_ * W_ + cc_) * 3);
            f4 t;
            t.x = ok ? v.x : 0.0f;
            t.y = ok ? v.y : 0.0f;
            t.z = ok ? v.z : 0.0f;
            t.w = 1.0f;                        // den rides .w via pk_fma
            float n2 = t.x * t.x;
            n2 = fmaf(t.y, t.y, n2);
            n2 = fmaf(t.z, t.z, n2);
            tile[s] = t;                       // ds_write_b128
            tileq[s] = NEG50L * n2;            // ds_write_b32
        }
    }
    __syncthreads();

    const int lane  = threadIdx.x & 63;        // column within tile
    const int wv    = threadIdx.x >> 6;        // wave -> 4-row group
    const int rbase = wv * TH;                 // first LDS row of my stream

    // per-center state: kc = 100L*c, qsp[6] = qc + spatial table,
    // packed accumulators with center tap (w==1) pre-folded.
    float kc[TH][3], qsp[TH][6];
    f2 accRG[TH], accB1[TH];
#pragma unroll
    for (int j = 0; j < TH; ++j) {
        const int ci = (rbase + j + 2) * LC + (lane + 2);
        const f4 c = tile[ci];
        const float qc = tileq[ci];
        kc[j][0] = M100L * c.x;
        kc[j][1] = M100L * c.y;
        kc[j][2] = M100L * c.z;
        qsp[j][0] = qc;
        qsp[j][1] = qc + (-0.5f * LOG2E) * 1.0f;
        qsp[j][2] = qc + (-0.5f * LOG2E) * 2.0f;
        qsp[j][3] = qc + (-0.5f * LOG2E) * 4.0f;
        qsp[j][4] = qc + (-0.5f * LOG2E) * 5.0f;
        qsp[j][5] = qc + (-0.5f * LOG2E) * 8.0f;
        accRG[j] = (f2){c.x, c.y};             // center tap (w==1) pre-folded
        accB1[j] = (f2){c.z, 1.0f};
    }

    // ---- stream 8 LDS rows; each serves the windows of up to 4 centers ----
#pragma unroll
    for (int r = 0; r < TH + 4; ++r) {
        f4 row[5];
        float rowq[5];
#pragma unroll
        for (int dx = 0; dx < 5; ++dx) {
            const int ti = (rbase + r) * LC + (lane + dx);
            row[dx] = tile[ti];                // ds_read_b128 (16B stride: dense)
            rowq[dx] = tileq[ti];              // ds_read_b32  (4B stride: dense)
        }

#pragma unroll
        for (int j = 0; j < TH; ++j) {
            if (r - j >= 0 && r - j <= 4) {    // unroll-const
                const int dy = r - j;
                const int sdy = (dy - 2) * (dy - 2);
#pragma unroll
                for (int dx = 0; dx < 5; ++dx) {
                    if (dy == 2 && dx == 2) continue;   // pre-folded center
                    const f4 n = row[dx];
                    float s = fmaf(n.x, kc[j][0], rowq[dx]);
                    s = fmaf(n.y, kc[j][1], s);
                    s = fmaf(n.z, kc[j][2], s);
                    const int si = sidx(sdy + (dx - 2) * (dx - 2));
                    const float arg = s + qsp[j][si];   // compile-time si
                    const float w = EXP2(arg);
                    const f2 w2 = {w, w};
                    const f2 nRG = {n.x, n.y};
                    const f2 nB1 = {n.z, n.w};          // {b, 1.0}
                    accRG[j] = __builtin_elementwise_fma(w2, nRG, accRG[j]);
                    accB1[j] = __builtin_elementwise_fma(w2, nB1, accB1[j]);
                }
            }
        }
    }

    // ---- epilogue: all outputs in-bounds by construction ----
#pragma unroll
    for (int j = 0; j < TH; ++j) {
        const float inv = __builtin_amdgcn_rcpf(accB1[j].y);   // den >= 1
        float* op = oimg + ((size_t)(h0 + rbase + j) * W_ + (c0 + lane)) * 3;
        op[0] = accRG[j].x * inv;
        op[1] = accRG[j].y * inv;
        op[2] = accB1[j].x * inv;
    }
}

extern "C" void kernel_launch(void* const* d_in, const int* in_sizes, int n_in,
                              void* d_out, int out_size, void* d_ws, size_t ws_size,
                              hipStream_t stream) {
    const float* x = (const float*)d_in[0];
    float* out = (float*)d_out;

    const int grid = B_ * (W_ / TILE_C) * (H_ / TILE_R);   // 16*8*32 = 4096
    const int block = 256;

    bilateral_kernel<<<grid, block, 0, stream>>>(x, out);
}